// Round 10
// baseline (186.495 us; speedup 1.0000x reference)
//
#include <hip/hip_runtime.h>
#include <hip/hip_bf16.h>
#include <stdint.h>

// QuantizedConv2d int8: x (32,128,56,56), w (256,128,3,3), pad 1, stride 1.
// Implicit GEMM on v_mfma_i32_32x32x32_i8. M=out-ch, N=pixels, K=9*128=1152.
// R10: R9's all-LDS K-loop (zero global loads / zero barriers), rebalanced:
// blocks of 7 rows x 448 threads, grid 1024 = exactly 4 blocks/CU.
// LDS 139 KB: lw 72 KB (all 9 taps, 64 ch) + lx 66.8 KB (9 padded rows).

#define NB   32
#define CIN  128
#define HO   56
#define WO   56
#define KOUT 256
#define HP   58
#define ROWB (HP * CIN)          // 7424 bytes per padded row

typedef int v4i  __attribute__((ext_vector_type(4)));
typedef int v16i __attribute__((ext_vector_type(16)));

static __device__ __forceinline__ void gload_lds16(const int8_t* g, int8_t* l) {
  __builtin_amdgcn_global_load_lds(
      (const __attribute__((address_space(1))) void*)g,
      (__attribute__((address_space(3))) void*)l, 16, 0, 0);
}

// ---------------- pack x: NCHW int32 -> padded NHWC int8 ----------------
__global__ __launch_bounds__(256) void pack_x_kernel(const int* __restrict__ x,
                                                     int8_t* __restrict__ xp) {
  __shared__ int t32[128][57];       // [c][w], stride 57
  const int tid = threadIdx.x;
  const int r = blockIdx.x;          // padded row 0..57
  const int n = blockIdx.y;
  const bool interior = (r >= 1) && (r <= HO);

  if (interior) {
    const int h = r - 1;
    const int* xrow = x + ((size_t)(n * CIN) * HO + h) * WO;  // c stride = 3136 ints
    #pragma unroll
    for (int it = 0; it < 7; ++it) {
      const int j = it * 256 + tid;  // < 1792 = 128 c x 14 w-quads
      const int c = j / 14;
      const int w4 = j - c * 14;
      const int4 v = *reinterpret_cast<const int4*>(xrow + c * 3136 + w4 * 4);
      t32[c][w4 * 4 + 0] = v.x;
      t32[c][w4 * 4 + 1] = v.y;
      t32[c][w4 * 4 + 2] = v.z;
      t32[c][w4 * 4 + 3] = v.w;
    }
  }
  __syncthreads();
  // write one padded row: 58 px x 8 chunk-quads as int4 (16 B/lane)
  #pragma unroll
  for (int it = 0; it < 2; ++it) {
    const int i = it * 256 + tid;
    if (i < HP * 8) {
      const int w = i >> 3;          // padded col 0..57
      const int q = i & 7;           // 16-byte quad (4 c4 words)
      int4 vv; vv.x = 0; vv.y = 0; vv.z = 0; vv.w = 0;
      if (interior && w >= 1 && w <= WO) {
        int vals[4];
        #pragma unroll
        for (int ci = 0; ci < 4; ++ci) {
          const int c4 = q * 4 + ci;
          const int b0 = t32[c4 * 4 + 0][w - 1] & 0xff;
          const int b1 = t32[c4 * 4 + 1][w - 1] & 0xff;
          const int b2 = t32[c4 * 4 + 2][w - 1] & 0xff;
          const int b3 = t32[c4 * 4 + 3][w - 1];
          vals[ci] = b0 | (b1 << 8) | (b2 << 16) | (b3 << 24);
        }
        vv.x = vals[0]; vv.y = vals[1]; vv.z = vals[2]; vv.w = vals[3];
      }
      *reinterpret_cast<int4*>(xp + ((size_t)(n * HP + r) * HP + w) * CIN + q * 16) = vv;
    }
  }
}

// ------ pack w: OIHW int32 -> [kt(4)][tap(9)][cc(8)][ch(64)] 16B chunks ------
__global__ __launch_bounds__(256) void pack_w_kernel(const int* __restrict__ wgt,
                                                     int8_t* __restrict__ wq) {
  const int wid = blockIdx.x * 256 + threadIdx.x;   // 0..73727 int32 words
  const int wi = wid & 3;
  const int ci = wid >> 2;                          // chunk 0..18431
  const int kt = ci / 4608;                         // 4608 = 9*8*64
  const int r  = ci - kt * 4608;
  const int tap = r >> 9;                           // 512 = 8*64
  const int r2  = r & 511;
  const int cc  = r2 >> 6;
  const int ch  = r2 & 63;
  const int k_global = kt * 64 + ch;
  const int cin0 = cc * 16 + wi * 4;
  const int base = (k_global * CIN + cin0) * 9 + tap;  // OIHW, 3x3=9 taps
  const int v0 = wgt[base];
  const int v1 = wgt[base + 9];
  const int v2 = wgt[base + 18];
  const int v3 = wgt[base + 27];
  reinterpret_cast<int*>(wq)[wid] =
      (v0 & 0xff) | ((v1 & 0xff) << 8) | ((v2 & 0xff) << 16) | (v3 << 24);
}

// ---------------- conv: all-LDS K-loop ----------------
// grid (4 kt, 8 rowgroups, 32 n) = 1024 blocks (exactly 4/CU), 448 thr = 7 waves.
// Block: 64 out-ch x 7 output rows. Wave wr: row h0+wr, 64 ch x 64 px.
// acc[mt][nt] = 64 AGPR. K-loop: 4 LDS b128 reads per 4 MFMAs, no barriers.
__global__ __launch_bounds__(448) void conv_kernel(const int8_t* __restrict__ xp,
                                                   const int8_t* __restrict__ wq,
                                                   const int* __restrict__ bias,
                                                   const float* __restrict__ wscale,
                                                   int* __restrict__ out) {
  __shared__ __align__(16) int8_t lw[9 * 8 * 64 * 16];  // 73,728 B: all taps, 64 ch
  __shared__ __align__(16) int8_t lx[9 * HP * 8 * 16];  // 66,816 B: 9 padded rows
  __shared__ int   bsh[64];
  __shared__ float ssh[64];

  const int tid = threadIdx.x;
  const int kt = blockIdx.x;           // 64-ch slice
  const int h0 = blockIdx.y * 7;
  const int n_img = blockIdx.z;

  const int lane = tid & 63;
  const int wr = tid >> 6;             // wave = output row 0..6
  const int p0 = lane & 31;
  const int half = lane >> 5;

  const int8_t* xg = xp + ((size_t)(n_img * HP) + h0) * ROWB;
  const int8_t* wqt = wq + (size_t)kt * 73728;

  // ---- stage weights: 4608 chunks, linear (layout pre-swizzled by pack_w) ----
  #pragma unroll
  for (int it = 0; it < 11; ++it) {
    const int j = it * 448 + tid;
    if (j < 4608) gload_lds16(wqt + j * 16, lw + j * 16);
  }
  // ---- stage pixels: 9 padded rows = 4176 chunks, XOR swizzle in source ----
  #pragma unroll
  for (int it = 0; it < 10; ++it) {
    const int i = it * 448 + tid;
    if (i < 9 * HP * 8) {
      const int pf = i >> 3;
      const int cc = (i & 7) ^ (pf & 7);
      gload_lds16(xg + pf * CIN + (cc << 4), lx + i * 16);
    }
  }
  if (tid < 64) {
    const int ch = kt * 64 + tid;
    bsh[tid] = bias[ch];
    ssh[tid] = (0.02f * wscale[ch]) / 0.05f;   // IN_SCALE * ws / OUT_SCALE
  }
  __syncthreads();

  v16i acc[2][2];                      // [mt: 32-ch tile][nt: 32-px tile]
  #pragma unroll
  for (int mt = 0; mt < 2; ++mt)
    #pragma unroll
    for (int nt = 0; nt < 2; ++nt)
      #pragma unroll
      for (int e = 0; e < 16; ++e) acc[mt][nt][e] = 0;

  #pragma unroll
  for (int tap = 0; tap < 9; ++tap) {
    const int kh = tap / 3, kw = tap % 3;
    const int8_t* lwt = lw + tap * 8192;         // [cc(8)][ch(64)] chunk-major
    const int pfb = (wr + kh) * HP + kw;
    #pragma unroll
    for (int ks = 0; ks < 4; ++ks) {
      const int cch = 2 * ks + half;             // k-chunk for this lane
      const v4i a0 = *reinterpret_cast<const v4i*>(lwt + cch * 1024 + p0 * 16);
      const v4i a1 = *reinterpret_cast<const v4i*>(lwt + cch * 1024 + (32 + p0) * 16);
      #pragma unroll
      for (int nt = 0; nt < 2; ++nt) {
        const int pf = pfb + nt * 32 + p0;
        const v4i b = *reinterpret_cast<const v4i*>(
            lx + pf * CIN + ((cch ^ (pf & 7)) << 4));
        acc[0][nt] = __builtin_amdgcn_mfma_i32_32x32x32_i8(a0, b, acc[0][nt], 0, 0, 0);
        acc[1][nt] = __builtin_amdgcn_mfma_i32_32x32x32_i8(a1, b, acc[1][nt], 0, 0, 0);
      }
    }
  }

  // ---- epilogue: D row = ch = mt*32 + (r&3)+8*(r>>2)+4*half, col = pixel ----
  const int h = h0 + wr;
  #pragma unroll
  for (int mt = 0; mt < 2; ++mt) {
    #pragma unroll
    for (int r = 0; r < 16; ++r) {
      const int cl = mt * 32 + (r & 3) + 8 * (r >> 2) + 4 * half;
      const int bi = bsh[cl];
      const float sc = ssh[cl];
      int* ob = out + (((size_t)(n_img * KOUT + kt * 64 + cl)) * HO + h) * WO;
      #pragma unroll
      for (int nt = 0; nt < 2; ++nt) {
        const int w = nt * 32 + p0;
        if (w < WO) {
          float v = (float)(acc[mt][nt][r] + bi) * sc;
          v = rintf(v);                          // round-half-even == jnp.round
          v = fminf(fmaxf(v, -128.0f), 127.0f);
          ob[w] = (int)v;
        }
      }
    }
  }
}

extern "C" void kernel_launch(void* const* d_in, const int* in_sizes, int n_in,
                              void* d_out, int out_size, void* d_ws, size_t ws_size,
                              hipStream_t stream) {
  const int* x = (const int*)d_in[0];
  const int* wgt = (const int*)d_in[1];
  const int* bias = (const int*)d_in[2];
  const float* wscale = (const float*)d_in[3];
  int* out = (int*)d_out;

  int8_t* xp = (int8_t*)d_ws;                               // 13,780,992 B
  int8_t* wq = (int8_t*)d_ws + (size_t)NB * HP * ROWB;      // 294,912 B

  pack_x_kernel<<<dim3(HP, NB), 256, 0, stream>>>(x, xp);
  pack_w_kernel<<<288, 256, 0, stream>>>(wgt, wq);
  conv_kernel<<<dim3(4, 8, 32), 448, 0, stream>>>(xp, wq, bias, wscale, out);
}

// Round 11
// 185.491 us; speedup vs baseline: 1.0054x; 1.0054x over previous
//
#include <hip/hip_runtime.h>
#include <hip/hip_bf16.h>
#include <stdint.h>

// QuantizedConv2d int8: x (32,128,56,56), w (256,128,3,3), pad 1, stride 1.
// Implicit GEMM on v_mfma_i32_32x32x32_i8. M=out-ch, N=pixels, K=9*128=1152.
// R11: persistent blocks — grid 256 (= 1 block/CU), each block keeps its 64-ch
// weight slice (72 KB LDS) and loops over 4 images, re-staging only lx.
// Software pipeline: epilogue(img i-1) stores issue right after the barrier and
// drain during K(img i) (dual acc sets), so no vmcnt(0) drain is exposed.

#define NB   32
#define CIN  128
#define HO   56
#define WO   56
#define KOUT 256
#define HP   58
#define ROWB (HP * CIN)          // 7424 bytes per padded row

typedef int v4i  __attribute__((ext_vector_type(4)));
typedef int v16i __attribute__((ext_vector_type(16)));

static __device__ __forceinline__ void gload_lds16(const int8_t* g, int8_t* l) {
  __builtin_amdgcn_global_load_lds(
      (const __attribute__((address_space(1))) void*)g,
      (__attribute__((address_space(3))) void*)l, 16, 0, 0);
}

// ---------------- pack x: NCHW int32 -> padded NHWC int8 ----------------
__global__ __launch_bounds__(256) void pack_x_kernel(const int* __restrict__ x,
                                                     int8_t* __restrict__ xp) {
  __shared__ int t32[128][57];       // [c][w], stride 57
  const int tid = threadIdx.x;
  const int r = blockIdx.x;          // padded row 0..57
  const int n = blockIdx.y;
  const bool interior = (r >= 1) && (r <= HO);

  if (interior) {
    const int h = r - 1;
    const int* xrow = x + ((size_t)(n * CIN) * HO + h) * WO;  // c stride = 3136 ints
    #pragma unroll
    for (int it = 0; it < 7; ++it) {
      const int j = it * 256 + tid;  // < 1792 = 128 c x 14 w-quads
      const int c = j / 14;
      const int w4 = j - c * 14;
      const int4 v = *reinterpret_cast<const int4*>(xrow + c * 3136 + w4 * 4);
      t32[c][w4 * 4 + 0] = v.x;
      t32[c][w4 * 4 + 1] = v.y;
      t32[c][w4 * 4 + 2] = v.z;
      t32[c][w4 * 4 + 3] = v.w;
    }
  }
  __syncthreads();
  // write one padded row: 58 px x 8 chunk-quads as int4 (16 B/lane)
  #pragma unroll
  for (int it = 0; it < 2; ++it) {
    const int i = it * 256 + tid;
    if (i < HP * 8) {
      const int w = i >> 3;          // padded col 0..57
      const int q = i & 7;           // 16-byte quad (4 c4 words)
      int4 vv; vv.x = 0; vv.y = 0; vv.z = 0; vv.w = 0;
      if (interior && w >= 1 && w <= WO) {
        int vals[4];
        #pragma unroll
        for (int ci = 0; ci < 4; ++ci) {
          const int c4 = q * 4 + ci;
          const int b0 = t32[c4 * 4 + 0][w - 1] & 0xff;
          const int b1 = t32[c4 * 4 + 1][w - 1] & 0xff;
          const int b2 = t32[c4 * 4 + 2][w - 1] & 0xff;
          const int b3 = t32[c4 * 4 + 3][w - 1];
          vals[ci] = b0 | (b1 << 8) | (b2 << 16) | (b3 << 24);
        }
        vv.x = vals[0]; vv.y = vals[1]; vv.z = vals[2]; vv.w = vals[3];
      }
      *reinterpret_cast<int4*>(xp + ((size_t)(n * HP + r) * HP + w) * CIN + q * 16) = vv;
    }
  }
}

// ------ pack w: OIHW int32 -> [kt(4)][tap(9)][cc(8)][ch(64)] 16B chunks ------
__global__ __launch_bounds__(256) void pack_w_kernel(const int* __restrict__ wgt,
                                                     int8_t* __restrict__ wq) {
  const int wid = blockIdx.x * 256 + threadIdx.x;   // 0..73727 int32 words
  const int wi = wid & 3;
  const int ci = wid >> 2;                          // chunk 0..18431
  const int kt = ci / 4608;                         // 4608 = 9*8*64
  const int r  = ci - kt * 4608;
  const int tap = r >> 9;                           // 512 = 8*64
  const int r2  = r & 511;
  const int cc  = r2 >> 6;
  const int ch  = r2 & 63;
  const int k_global = kt * 64 + ch;
  const int cin0 = cc * 16 + wi * 4;
  const int base = (k_global * CIN + cin0) * 9 + tap;  // OIHW, 3x3=9 taps
  const int v0 = wgt[base];
  const int v1 = wgt[base + 9];
  const int v2 = wgt[base + 18];
  const int v3 = wgt[base + 27];
  reinterpret_cast<int*>(wq)[wid] =
      (v0 & 0xff) | ((v1 << 8) & 0xff00) | ((v2 << 16) & 0xff0000) | (v3 << 24);
}

// ---------------- conv: persistent block, all-LDS K-loop ----------------
// grid (4 kt, 8 rowgr, 8 ngroups) = 256 blocks = 1/CU, 448 thr = 7 waves.
// Block: 64 out-ch x 7 output rows x 4 images (looped). Wave wr: one row.
__global__ __launch_bounds__(448) void conv_kernel(const int8_t* __restrict__ xp,
                                                   const int8_t* __restrict__ wq,
                                                   const int* __restrict__ bias,
                                                   const float* __restrict__ wscale,
                                                   int* __restrict__ out) {
  __shared__ __align__(16) int8_t lw[9 * 8 * 64 * 16];  // 73,728 B: all taps, 64 ch
  __shared__ __align__(16) int8_t lx[9 * HP * 8 * 16];  // 66,816 B: 9 padded rows
  __shared__ int   bsh[64];
  __shared__ float ssh[64];

  const int tid = threadIdx.x;
  const int kt = blockIdx.x;           // 64-ch slice
  const int h0 = blockIdx.y * 7;
  const int n0 = blockIdx.z * 4;       // first image of this block's group

  const int lane = tid & 63;
  const int wr = tid >> 6;             // wave = output row 0..6
  const int p0 = lane & 31;
  const int half = lane >> 5;

  const int8_t* wqt = wq + (size_t)kt * 73728;

  // ---- stage weights once ----
  #pragma unroll
  for (int it = 0; it < 11; ++it) {
    const int j = it * 448 + tid;
    if (j < 4608) gload_lds16(wqt + j * 16, lw + j * 16);
  }
  if (tid < 64) {
    const int ch = kt * 64 + tid;
    bsh[tid] = bias[ch];
    ssh[tid] = (0.02f * wscale[ch]) / 0.05f;   // IN_SCALE * ws / OUT_SCALE
  }

#define STAGE_LX(i)                                                           \
  {                                                                           \
    const int8_t* xg = xp + ((size_t)((n0 + (i)) * HP) + h0) * ROWB;          \
    _Pragma("unroll")                                                         \
    for (int it = 0; it < 10; ++it) {                                         \
      const int j = it * 448 + tid;                                           \
      if (j < 9 * HP * 8) {                                                   \
        const int pf = j >> 3;                                                \
        const int cc = (j & 7) ^ (pf & 7);                                    \
        gload_lds16(xg + pf * CIN + (cc << 4), lx + j * 16);                  \
      }                                                                       \
    }                                                                         \
  }

#define KLOOP(acc)                                                            \
  {                                                                           \
    _Pragma("unroll")                                                         \
    for (int mt = 0; mt < 2; ++mt)                                            \
      _Pragma("unroll")                                                       \
      for (int nt = 0; nt < 2; ++nt)                                          \
        _Pragma("unroll")                                                     \
        for (int e = 0; e < 16; ++e) acc[mt][nt][e] = 0;                      \
    _Pragma("unroll")                                                         \
    for (int tap = 0; tap < 9; ++tap) {                                       \
      const int kh = tap / 3, kw = tap % 3;                                   \
      const int8_t* lwt = lw + tap * 8192;       /* [cc(8)][ch(64)] */        \
      const int pfb = (wr + kh) * HP + kw;                                    \
      _Pragma("unroll")                                                       \
      for (int ks = 0; ks < 4; ++ks) {                                        \
        const int cch = 2 * ks + half;                                        \
        const v4i a0 = *reinterpret_cast<const v4i*>(lwt + cch * 1024 + p0 * 16); \
        const v4i a1 = *reinterpret_cast<const v4i*>(lwt + cch * 1024 + (32 + p0) * 16); \
        _Pragma("unroll")                                                     \
        for (int nt = 0; nt < 2; ++nt) {                                      \
          const int pf = pfb + nt * 32 + p0;                                  \
          const v4i b = *reinterpret_cast<const v4i*>(                        \
              lx + pf * CIN + ((cch ^ (pf & 7)) << 4));                       \
          acc[0][nt] = __builtin_amdgcn_mfma_i32_32x32x32_i8(a0, b, acc[0][nt], 0, 0, 0); \
          acc[1][nt] = __builtin_amdgcn_mfma_i32_32x32x32_i8(a1, b, acc[1][nt], 0, 0, 0); \
        }                                                                     \
      }                                                                       \
    }                                                                         \
  }

#define EPILOGUE(acc, i)                                                      \
  {                                                                           \
    const int h = h0 + wr;                                                    \
    _Pragma("unroll")                                                         \
    for (int mt = 0; mt < 2; ++mt) {                                          \
      _Pragma("unroll")                                                       \
      for (int r = 0; r < 16; ++r) {                                          \
        const int cl = mt * 32 + (r & 3) + 8 * (r >> 2) + 4 * half;           \
        const int bi = bsh[cl];                                               \
        const float sc = ssh[cl];                                             \
        int* ob = out + (((size_t)((n0 + (i)) * KOUT + kt * 64 + cl)) * HO + h) * WO; \
        _Pragma("unroll")                                                     \
        for (int nt = 0; nt < 2; ++nt) {                                      \
          const int w = nt * 32 + p0;                                         \
          if (w < WO) {                                                       \
            float v = (float)(acc[mt][nt][r] + bi) * sc;                      \
            v = rintf(v);                        /* RNE == jnp.round */       \
            v = fminf(fmaxf(v, -128.0f), 127.0f);                             \
            ob[w] = (int)v;                                                   \
          }                                                                   \
        }                                                                     \
      }                                                                       \
    }                                                                         \
  }

  v16i accA[2][2], accB[2][2];

  STAGE_LX(0);
  __syncthreads();               // staging(0)+lw drained
  KLOOP(accA);                   // img 0
  __syncthreads();               // all waves done reading lx(0); no stores in flight
  STAGE_LX(1);
  __syncthreads();               // staging(1) drained
  EPILOGUE(accA, 0);             // stores drain during K(1)
  KLOOP(accB);                   // img 1
  __syncthreads();
  STAGE_LX(2);
  __syncthreads();
  EPILOGUE(accB, 1);
  KLOOP(accA);                   // img 2
  __syncthreads();
  STAGE_LX(3);
  __syncthreads();
  EPILOGUE(accA, 2);
  KLOOP(accB);                   // img 3
  EPILOGUE(accB, 3);

#undef STAGE_LX
#undef KLOOP
#undef EPILOGUE
}

extern "C" void kernel_launch(void* const* d_in, const int* in_sizes, int n_in,
                              void* d_out, int out_size, void* d_ws, size_t ws_size,
                              hipStream_t stream) {
  const int* x = (const int*)d_in[0];
  const int* wgt = (const int*)d_in[1];
  const int* bias = (const int*)d_in[2];
  const float* wscale = (const float*)d_in[3];
  int* out = (int*)d_out;

  int8_t* xp = (int8_t*)d_ws;                               // 13,780,992 B
  int8_t* wq = (int8_t*)d_ws + (size_t)NB * HP * ROWB;      // 294,912 B

  pack_x_kernel<<<dim3(HP, NB), 256, 0, stream>>>(x, xp);
  pack_w_kernel<<<288, 256, 0, stream>>>(wgt, wq);
  conv_kernel<<<dim3(4, 8, 8), 448, 0, stream>>>(xp, wq, bias, wscale, out);
}